// Round 5
// baseline (254.831 us; speedup 1.0000x reference)
//
#include <hip/hip_runtime.h>

#define F 16
#define BSHIFT 6
#define NPB 64            // nodes per bucket
#define NB 1563           // buckets for N=100000
#define CH 4096           // edges per reorder block
#define BCAP 2304         // padded per-bucket edge capacity (mean 2048, sd ~45)

// ========================= fast path kernels ================================

__global__ void init_cursor_kernel(unsigned* __restrict__ cursor) {
    int i = blockIdx.x * 512 + threadIdx.x;
    if (i < NB) cursor[i * 16] = (unsigned)(i * BCAP);
}

// bucket reorder via rank-trick counting sort to 1563 fine buckets.
// 512 threads, 1 LDS-atomic pass, src cached in registers.
// rec = src | (dst&63)<<17
__global__ __launch_bounds__(512) void
reorder_kernel(const int* __restrict__ src, const int* __restrict__ dst,
               unsigned* __restrict__ cursor, unsigned* __restrict__ recs, int E) {
    __shared__ unsigned lsorted[CH];
    __shared__ unsigned short lbkt[CH];
    __shared__ unsigned cnt[NB];       // counts; later reused as global run base
    __shared__ unsigned lstart[NB + 1];
    int t = threadIdx.x, b = blockIdx.x;
    int e0 = b * CH;
    int cnt_e = E - e0; if (cnt_e > CH) cnt_e = CH;

    for (int i = t; i < NB; i += 512) cnt[i] = 0;
    __syncthreads();
    // phase 1: histogram + per-edge (bucket,low,rank); src kept in registers
    unsigned pk[8], rs[8];
#pragma unroll
    for (int j = 0; j < 8; ++j) {
        int i = t + j * 512;
        pk[j] = 0xFFFFFFFFu;
        if (i < cnt_e) {
            unsigned d = (unsigned)dst[e0 + i];
            rs[j] = (unsigned)src[e0 + i];
            unsigned bk = d >> BSHIFT;
            unsigned r = atomicAdd(&cnt[bk], 1u);
            pk[j] = bk | ((d & 63u) << 11) | (r << 17);   // bk:11 | low:6 | rank
        }
    }
    __syncthreads();
    // phase 2: exclusive scan of NB counts by wave 0
    if (t < 64) {
        unsigned run = 0;
        for (int c = 0; c < NB; c += 64) {
            int idx = c + t;
            unsigned v = (idx < NB) ? cnt[idx] : 0u;
            unsigned inc = v;
#pragma unroll
            for (int d = 1; d < 64; d <<= 1) {
                unsigned o = __shfl_up(inc, d, 64);
                if (t >= d) inc += o;
            }
            if (idx < NB) lstart[idx] = run + inc - v;
            run += __shfl(inc, 63, 64);
        }
        if (t == 0) lstart[NB] = (unsigned)cnt_e;
    }
    __syncthreads();
    // phase 3: reserve global run per touched bucket (staggered sweep start)
    {
        int s0 = (int)(((unsigned)b * 101u) % (unsigned)NB);
        for (int q = t; q < NB; q += 512) {
            int i = s0 + q; if (i >= NB) i -= NB;
            unsigned c = cnt[i];
            if (c) cnt[i] = atomicAdd(&cursor[i * 16], c);
        }
    }
    __syncthreads();
    // phase 4: non-atomic LDS scatter from registers
#pragma unroll
    for (int j = 0; j < 8; ++j) {
        int i = t + j * 512;
        if (i < cnt_e) {
            unsigned p = pk[j];
            unsigned bk = p & 0x7FFu;
            unsigned pos = lstart[bk] + (p >> 17);
            lsorted[pos] = rs[j] | (((p >> 11) & 63u) << 17);
            lbkt[pos] = (unsigned short)bk;
        }
    }
    __syncthreads();
    // phase 5: run-contiguous global write-out
    for (int i = t; i < cnt_e; i += 512) {
        unsigned bk = lbkt[i];
        recs[cnt[bk] + ((unsigned)i - lstart[bk])] = lsorted[i];
    }
}

// per-fine-bucket (src-half, node) sort via rank-trick, 128 bins, 512 threads,
// 1563 blocks (6.1/CU). Emits split CSR (A: src<NH, B: src>=NH), dinv, sorted
// srcs (node kept in bits [17:23)), fused z = x*dinv.
__global__ __launch_bounds__(512) void
sort2_kernel(const unsigned* __restrict__ recs, const unsigned* __restrict__ cursor,
             unsigned* __restrict__ srcs,
             int* __restrict__ noffA, int* __restrict__ nendA,
             int* __restrict__ noffB, int* __restrict__ nendB,
             float* __restrict__ dinv, const float* __restrict__ x,
             float* __restrict__ z, int n) {
    __shared__ unsigned lsort[BCAP];
    __shared__ unsigned cnt[128];
    __shared__ unsigned ex[128];
    __shared__ float ldv[NPB];
    __shared__ unsigned wtot[2];
    int t = threadIdx.x, b = blockIdx.x;
    int e0 = b * BCAP;
    int used = (int)(cursor[b * 16] - (unsigned)e0);
    unsigned NH = ((unsigned)n + 1u) >> 1;
    if (t < 128) cnt[t] = 0;
    __syncthreads();
    // phase 1: per-(half,node) histogram + rank; record kept in registers
    unsigned pk[5], rsr[5];
#pragma unroll
    for (int j = 0; j < 5; ++j) {
        int i = t + j * 512;
        pk[j] = 0xFFFFFFFFu;
        if (i < used) {
            unsigned rec = recs[e0 + i];
            unsigned node = rec >> 17;                       // 0..63
            unsigned half = ((rec & 0x1FFFFu) >= NH) ? 1u : 0u;
            unsigned bin = (half << 6) | node;               // 0..127
            rsr[j] = rec;
            unsigned r = atomicAdd(&cnt[bin], 1u);
            pk[j] = bin | (r << 7);
        }
    }
    __syncthreads();
    // phase 2: 128-entry exclusive scan (2 waves) + split-CSR emit
    {
        unsigned c = 0, inc = 0;
        int lane = t & 63, w = t >> 6;
        if (t < 128) {
            c = cnt[t];
            inc = c;
#pragma unroll
            for (int d = 1; d < 64; d <<= 1) {
                unsigned o = __shfl_up(inc, d, 64);
                if (lane >= d) inc += o;
            }
            if (lane == 63) wtot[w] = inc;
        }
        __syncthreads();
        if (t < 128) {
            unsigned base = (w == 1) ? wtot[0] : 0u;
            unsigned e = base + inc - c;
            ex[t] = e;
            int node = t & 63, half = t >> 6;
            int gnode = b * NPB + node;
            if (gnode < n) {
                if (half == 0) { noffA[gnode] = e0 + (int)e; nendA[gnode] = e0 + (int)(e + c); }
                else           { noffB[gnode] = e0 + (int)e; nendB[gnode] = e0 + (int)(e + c); }
            }
        }
    }
    __syncthreads();
    if (t < NPB) {
        unsigned ctot = cnt[t] + cnt[64 + t];
        float dv = rsqrtf((float)ctot + 1.0f);
        ldv[t] = dv;
        int gnode = b * NPB + t;
        if (gnode < n) dinv[gnode] = dv;
    }
    __syncthreads();
    // phase 3: non-atomic LDS scatter from registers
#pragma unroll
    for (int j = 0; j < 5; ++j) {
        int i = t + j * 512;
        if (i < used) {
            unsigned p = pk[j];
            lsort[ex[p & 127u] + (p >> 7)] = rsr[j];
        }
    }
    __syncthreads();
    // phase 4: coalesced write-out
    for (int i = t; i < used; i += 512) srcs[e0 + i] = lsort[i];
    // phase 5 (fused): z = x * dinv for this block's 64 nodes (1 float4/thread)
    if (t < NPB * 4) {
        int node = b * NPB + (t >> 2);
        if (node < n) {
            float4 v = ((const float4*)x)[(size_t)b * (NPB * 4) + t];
            float dv = ldv[t >> 2];
            v.x *= dv; v.y *= dv; v.z *= dv; v.w *= dv;
            ((float4*)z)[(size_t)b * (NPB * 4) + t] = v;
        }
    }
}

// two-phase merge-path segmented CSR aggregation — 64 nodes/block == 1 bucket,
// 256 threads. Pass A: src < NH (gather table = lower 3.2MB, per-XCD-L2-fits);
// pass B: src >= NH. Register accumulation, LDS-atomic flush only at segment
// boundaries; 8 gathers in flight per lane.
// mode 1: out = relu(dinv*(S@W) + bias) * dinv     (layer-1 -> y)
// mode 2: out = dinv*(S@W) + bias                  (final output)
__global__ __launch_bounds__(256) void
agg_bal_kernel(const float* __restrict__ hin, const unsigned* __restrict__ srcs,
               const int* __restrict__ noffA, const int* __restrict__ nendA,
               const int* __restrict__ noffB, const int* __restrict__ nendB,
               const float* __restrict__ dinv,
               const float* __restrict__ W, const float* __restrict__ bias,
               float* __restrict__ outp, int n, int mode) {
    __shared__ float acc[64][F + 1];
    __shared__ float Ws[F * F];
    int t = threadIdx.x, b = blockIdx.x;
    int g = t >> 2, c = t & 3;          // 64 groups of 4 lanes (float4 columns)
    Ws[t] = W[t];
    for (int i = t; i < 64 * (F + 1); i += 256) ((float*)acc)[i] = 0.f;
    __syncthreads();
    int nfirst = b * 64;
    int nlast = nfirst + 63; if (nlast > n - 1) nlast = n - 1;
    int rs0 = noffA[nfirst], re0 = nendA[nlast];
    int rs1 = noffB[nfirst], re1 = nendB[nlast];
    const float4* h4 = (const float4*)hin;

#define PROC(r, v)                                                        \
    {                                                                     \
        int nd = (int)((r >> 17) & 63u);                                  \
        if (nd != cur) {                                                  \
            float* a = &acc[cur][c * 4];                                  \
            atomicAdd(a + 0, s.x); atomicAdd(a + 1, s.y);                 \
            atomicAdd(a + 2, s.z); atomicAdd(a + 3, s.w);                 \
            s.x = 0.f; s.y = 0.f; s.z = 0.f; s.w = 0.f;                   \
            cur = nd;                                                     \
        }                                                                 \
        s.x += v.x; s.y += v.y; s.z += v.z; s.w += v.w;                   \
    }

#pragma unroll 1
    for (int p = 0; p < 2; ++p) {
        int S = p ? rs1 : rs0;
        int Eend = p ? re1 : re0;
        int T = Eend - S;
        int chunk = (T + 63) >> 6;
        int gs = S + g * chunk;
        int ge = gs + chunk; if (ge > Eend) ge = Eend;
        if (gs < ge) {
            int cur = (int)((srcs[gs] >> 17) & 63u);
            float4 s = {0.f, 0.f, 0.f, 0.f};
            int e = gs;
            for (; e + 8 <= ge; e += 8) {
                unsigned r0 = srcs[e + 0], r1 = srcs[e + 1];
                unsigned r2 = srcs[e + 2], r3 = srcs[e + 3];
                unsigned r4 = srcs[e + 4], r5 = srcs[e + 5];
                unsigned r6 = srcs[e + 6], r7 = srcs[e + 7];
                float4 v0 = h4[(size_t)(r0 & 0x1FFFFu) * 4 + c];
                float4 v1 = h4[(size_t)(r1 & 0x1FFFFu) * 4 + c];
                float4 v2 = h4[(size_t)(r2 & 0x1FFFFu) * 4 + c];
                float4 v3 = h4[(size_t)(r3 & 0x1FFFFu) * 4 + c];
                float4 v4 = h4[(size_t)(r4 & 0x1FFFFu) * 4 + c];
                float4 v5 = h4[(size_t)(r5 & 0x1FFFFu) * 4 + c];
                float4 v6 = h4[(size_t)(r6 & 0x1FFFFu) * 4 + c];
                float4 v7 = h4[(size_t)(r7 & 0x1FFFFu) * 4 + c];
                PROC(r0, v0); PROC(r1, v1); PROC(r2, v2); PROC(r3, v3);
                PROC(r4, v4); PROC(r5, v5); PROC(r6, v6); PROC(r7, v7);
            }
            for (; e + 4 <= ge; e += 4) {
                unsigned r0 = srcs[e], r1 = srcs[e + 1], r2 = srcs[e + 2], r3 = srcs[e + 3];
                float4 v0 = h4[(size_t)(r0 & 0x1FFFFu) * 4 + c];
                float4 v1 = h4[(size_t)(r1 & 0x1FFFFu) * 4 + c];
                float4 v2 = h4[(size_t)(r2 & 0x1FFFFu) * 4 + c];
                float4 v3 = h4[(size_t)(r3 & 0x1FFFFu) * 4 + c];
                PROC(r0, v0); PROC(r1, v1); PROC(r2, v2); PROC(r3, v3);
            }
            for (; e < ge; ++e) {
                unsigned r0 = srcs[e];
                float4 v0 = h4[(size_t)(r0 & 0x1FFFFu) * 4 + c];
                PROC(r0, v0);
            }
            float* a = &acc[cur][c * 4];
            atomicAdd(a + 0, s.x); atomicAdd(a + 1, s.y);
            atomicAdd(a + 2, s.z); atomicAdd(a + 3, s.w);
        }
        __syncthreads();   // phase alignment across the block's waves
    }
#undef PROC
    int node = nfirst + g;
    if (node < n) {   // self contribution (unique 4 floats per thread)
        float4 self = h4[(size_t)node * 4 + c];
        float* ar = &acc[g][c * 4];
        ar[0] += self.x; ar[1] += self.y; ar[2] += self.z; ar[3] += self.w;
    }
    __syncthreads();
    if (node < n) {
        float di = dinv[node];
        float4 o = {0.f, 0.f, 0.f, 0.f};
        int j = c * 4;
#pragma unroll
        for (int k = 0; k < F; ++k) {
            float ak = acc[g][k];
            o.x += ak * Ws[k * F + j + 0];
            o.y += ak * Ws[k * F + j + 1];
            o.z += ak * Ws[k * F + j + 2];
            o.w += ak * Ws[k * F + j + 3];
        }
        float4 bi = ((const float4*)bias)[c];
        o.x = di * o.x + bi.x; o.y = di * o.y + bi.y;
        o.z = di * o.z + bi.z; o.w = di * o.w + bi.w;
        if (mode == 1) {
            o.x = fmaxf(o.x, 0.f) * di; o.y = fmaxf(o.y, 0.f) * di;
            o.z = fmaxf(o.z, 0.f) * di; o.w = fmaxf(o.w, 0.f) * di;
        }
        ((float4*)outp)[(size_t)node * 4 + c] = o;
    }
}

// ========================= fallback (R1) kernels ============================

__global__ void deg_kernel(const int* __restrict__ dst, float* __restrict__ deg, int E) {
    int e = blockIdx.x * blockDim.x + threadIdx.x;
    if (e < E) atomicAdd(&deg[dst[e]], 1.0f);
}
__global__ void dinv_kernel(float* __restrict__ deg, int n) {
    int i = blockIdx.x * blockDim.x + threadIdx.x;
    if (i < n) deg[i] = rsqrtf(deg[i] + 1.0f);
}
__global__ void linear2_kernel(const float* __restrict__ in, const float* __restrict__ acc,
                               const float* __restrict__ dinv, const float* __restrict__ W,
                               const float* __restrict__ bias, float* __restrict__ out,
                               int n, int mode) {
    __shared__ float Ws[F * F];
    __shared__ float As[16][F + 1];
    int t = threadIdx.x;
    Ws[t] = W[t];
    int nb = t >> 4, j = t & 15;
    int i = blockIdx.x * 16 + nb;
    float di = 0.f, v = 0.f;
    if (i < n) {
        di = dinv[i]; v = in[i * F + j];
        if (mode) { v = di * (acc[i * F + j] + v) + bias[j]; v = fmaxf(v, 0.f); }
    }
    As[nb][j] = v;
    __syncthreads();
    if (i < n) {
        float s = 0.f;
#pragma unroll
        for (int k = 0; k < F; ++k) s += As[nb][k] * Ws[k * F + j];
        out[i * F + j] = s * di;
    }
}
__global__ void scatter_kernel(const int* __restrict__ src, const int* __restrict__ dst,
                               const float* __restrict__ h, float* __restrict__ acc, int E) {
    int t = blockIdx.x * blockDim.x + threadIdx.x;
    int e = t >> 4, j = t & 15;
    if (e < E) atomicAdd(&acc[dst[e] * F + j], h[src[e] * F + j]);
}
__global__ void out_kernel(const float* __restrict__ acc, const float* __restrict__ h,
                           const float* __restrict__ dinv, const float* __restrict__ bias,
                           float* __restrict__ out, int n) {
    int t = blockIdx.x * blockDim.x + threadIdx.x;
    if (t < n * F) {
        int i = t >> 4, j = t & 15;
        out[t] = dinv[i] * (acc[t] + h[t]) + bias[j];
    }
}

// ========================= launch ===========================================

extern "C" void kernel_launch(void* const* d_in, const int* in_sizes, int n_in,
                              void* d_out, int out_size, void* d_ws, size_t ws_size,
                              hipStream_t stream) {
    const float* x  = (const float*)d_in[0];
    const int*   ei = (const int*)d_in[1];
    const float* W1 = (const float*)d_in[2];
    const float* b1 = (const float*)d_in[3];
    const float* W2 = (const float*)d_in[4];
    const float* b2 = (const float*)d_in[5];
    float* outp = (float*)d_out;

    const int N = in_sizes[0] / F;
    const int E = in_sizes[1] / 2;
    const int* src = ei;
    const int* dst = ei + E;

    const int nb_rt = (N + NPB - 1) >> BSHIFT;
    const size_t RC = (size_t)NB * BCAP;           // 3,601,152 entries (> 16N)
    // ws layout (4B units): dinv[N] | z[16N] | recs[RC] (y aliases) | srcs[RC] |
    //                       noffA[N] | nendA[N] | noffB[N] | nendB[N] | cursor[16*NB]
    size_t need = sizeof(unsigned) * ((size_t)N * 21 + 2 * RC + 16 * NB);

    if (nb_rt == NB && E <= CH * 65535 && ws_size >= need) {
        float* dinv = (float*)d_ws;
        float* z = dinv + N;
        unsigned* recs = (unsigned*)(z + (size_t)F * N);
        float* y = (float*)recs;                   // alias: recs dead after sort2
        unsigned* srcs = recs + RC;
        int* noffA = (int*)(srcs + RC);
        int* nendA = noffA + N;
        int* noffB = nendA + N;
        int* nendB = noffB + N;
        unsigned* cursor = (unsigned*)(nendB + N);

        init_cursor_kernel<<<(NB + 511) / 512, 512, 0, stream>>>(cursor);
        reorder_kernel<<<(E + CH - 1) / CH, 512, 0, stream>>>(src, dst, cursor, recs, E);
        sort2_kernel<<<NB, 512, 0, stream>>>(recs, cursor, srcs, noffA, nendA, noffB, nendB, dinv, x, z, N);
        agg_bal_kernel<<<NB, 256, 0, stream>>>(z, srcs, noffA, nendA, noffB, nendB, dinv, W1, b1, y, N, 1);
        agg_bal_kernel<<<NB, 256, 0, stream>>>(y, srcs, noffA, nendA, noffB, nendB, dinv, W2, b2, outp, N, 2);
    } else {
        // R1 fallback: atomic scatter path (13.2MB ws)
        float* dinv = (float*)d_ws;
        float* h = dinv + N;
        float* acc = h + (size_t)F * N;
        hipMemsetAsync(dinv, 0, (size_t)N * sizeof(float), stream);
        hipMemsetAsync(acc, 0, (size_t)F * N * sizeof(float), stream);
        deg_kernel<<<(E + 255) / 256, 256, 0, stream>>>(dst, dinv, E);
        dinv_kernel<<<(N + 255) / 256, 256, 0, stream>>>(dinv, N);
        linear2_kernel<<<(N + 15) / 16, 256, 0, stream>>>(x, nullptr, dinv, W1, nullptr, h, N, 0);
        scatter_kernel<<<((size_t)E * F + 255) / 256, 256, 0, stream>>>(src, dst, h, acc, E);
        linear2_kernel<<<(N + 15) / 16, 256, 0, stream>>>(h, acc, dinv, W2, b1, h, N, 1);
        hipMemsetAsync(acc, 0, (size_t)F * N * sizeof(float), stream);
        scatter_kernel<<<((size_t)E * F + 255) / 256, 256, 0, stream>>>(src, dst, h, acc, E);
        out_kernel<<<((size_t)N * F + 255) / 256, 256, 0, stream>>>(acc, h, dinv, b2, outp, N);
    }
}

// Round 6
// 209.907 us; speedup vs baseline: 1.2140x; 1.2140x over previous
//
#include <hip/hip_runtime.h>

#define F 16
#define BSHIFT 8
#define NPB 256           // nodes per coarse bucket
#define NB 391            // coarse buckets for N=100000
#define CH 4096           // edges per reorder block
#define BCAP 9216         // padded per-bucket edge capacity (mean 8192, ~11 sd)
#define HCAP 4608         // padded per-half-bucket capacity (mean 4096, 8 sd)

// ========================= fast path kernels ================================

__global__ void init_cursor_kernel(unsigned* __restrict__ cursor) {
    int i = threadIdx.x;
    if (i < NB) cursor[i * 16] = (unsigned)(i * BCAP);
}

// bucket reorder via rank-trick counting sort. 512 threads, 1 LDS-atomic pass,
// src cached in registers (no re-read). rec = src | (dst&255)<<17
__global__ __launch_bounds__(512) void
reorder_kernel(const int* __restrict__ src, const int* __restrict__ dst,
               unsigned* __restrict__ cursor, unsigned* __restrict__ recs, int E) {
    __shared__ unsigned lsorted[CH];
    __shared__ unsigned short lbkt[CH];
    __shared__ unsigned cnt[NB];       // counts; later reused as global run base
    __shared__ unsigned lstart[NB + 1];
    int t = threadIdx.x, b = blockIdx.x;
    int e0 = b * CH;
    int cnt_e = E - e0; if (cnt_e > CH) cnt_e = CH;

    for (int i = t; i < NB; i += 512) cnt[i] = 0;
    __syncthreads();
    // phase 1: histogram + per-edge (bucket,low,rank) and src kept in registers
    unsigned pk[8], rs[8];
#pragma unroll
    for (int j = 0; j < 8; ++j) {
        int i = t + j * 512;
        pk[j] = 0xFFFFFFFFu;
        if (i < cnt_e) {
            unsigned d = (unsigned)dst[e0 + i];
            rs[j] = (unsigned)src[e0 + i];
            unsigned bk = d >> BSHIFT;
            unsigned r = atomicAdd(&cnt[bk], 1u);
            pk[j] = bk | ((d & 255u) << 9) | (r << 17);   // bk:9 | low:8 | rank:12
        }
    }
    __syncthreads();
    // phase 2: exclusive scan of NB counts by wave 0
    if (t < 64) {
        unsigned run = 0;
        for (int c = 0; c < NB; c += 64) {
            int idx = c + t;
            unsigned v = (idx < NB) ? cnt[idx] : 0u;
            unsigned inc = v;
#pragma unroll
            for (int d = 1; d < 64; d <<= 1) {
                unsigned o = __shfl_up(inc, d, 64);
                if (t >= d) inc += o;
            }
            if (idx < NB) lstart[idx] = run + inc - v;
            run += __shfl(inc, 63, 64);
        }
        if (t == 0) lstart[NB] = (unsigned)cnt_e;
    }
    __syncthreads();
    // phase 3: reserve global run per touched bucket (staggered sweep start to
    // decorrelate cursor-line contention across blocks); cnt[i] becomes base
    {
        int s0 = (int)(((unsigned)b * 101u) % (unsigned)NB);
        for (int q = t; q < NB; q += 512) {
            int i = s0 + q; if (i >= NB) i -= NB;
            unsigned c = cnt[i];
            if (c) cnt[i] = atomicAdd(&cursor[i * 16], c);
        }
    }
    __syncthreads();
    // phase 4: non-atomic LDS scatter from registers
#pragma unroll
    for (int j = 0; j < 8; ++j) {
        int i = t + j * 512;
        if (i < cnt_e) {
            unsigned p = pk[j];
            unsigned bk = p & 0x1FFu;
            unsigned pos = lstart[bk] + (p >> 17);
            lsorted[pos] = rs[j] | (((p >> 9) & 255u) << 17);
            lbkt[pos] = (unsigned short)bk;
        }
    }
    __syncthreads();
    // phase 5: run-contiguous global write-out
    for (int i = t; i < cnt_e; i += 512) {
        unsigned bk = lbkt[i];
        recs[cnt[bk] + ((unsigned)i - lstart[bk])] = lsorted[i];
    }
}

// half-bucket (src-half, node) sort — 782 blocks (2 per coarse bucket), 512
// threads, ~21KB LDS so ALL blocks co-resident (fixes R4 sort2's 1.5-block/CU
// packing). Streams the bucket's recs twice (filter to own 128-node half;
// L2-hot re-read), 256-bin hist+scan, rank-scatter, coalesced write-out.
// Emits split CSR (A: src<NH, B: src>=NH), dinv, fused z = x*dinv.
__global__ __launch_bounds__(512) void
sort2_kernel(const unsigned* __restrict__ recs, const unsigned* __restrict__ cursor,
             unsigned* __restrict__ srcs,
             int* __restrict__ noffA, int* __restrict__ nendA,
             int* __restrict__ noffB, int* __restrict__ nendB,
             float* __restrict__ dinv, const float* __restrict__ x,
             float* __restrict__ z, int n) {
    __shared__ unsigned lsort[HCAP];
    __shared__ unsigned cnt[256];
    __shared__ unsigned ex[256];
    __shared__ float ldv[128];
    __shared__ unsigned wtot[4];
    __shared__ unsigned tot_s;
    int t = threadIdx.x, b = blockIdx.x;
    int bucket = b >> 1, h = b & 1;
    int e0 = bucket * BCAP;
    int o0 = b * HCAP;                         // output base (b = bucket*2+h)
    int used = (int)(cursor[bucket * 16] - (unsigned)e0);
    unsigned NH = ((unsigned)n + 1u) >> 1;
    if (t < 256) cnt[t] = 0;
    __syncthreads();
    // pass 1: filtered histogram over (srcHalf, node&127)
    for (int i = t; i < used; i += 512) {
        unsigned rec = recs[e0 + i];
        unsigned node = rec >> 17;                       // 0..255 in bucket
        if ((int)(node >> 7) == h) {
            unsigned bin = (((rec & 0x1FFFFu) >= NH) ? 128u : 0u) | (node & 127u);
            atomicAdd(&cnt[bin], 1u);
        }
    }
    __syncthreads();
    // scan of 256 bins (4 waves) + split-CSR emit + dinv
    {
        unsigned c = 0, inc = 0;
        int lane = t & 63, w = t >> 6;
        if (t < 256) {
            c = cnt[t];
            inc = c;
#pragma unroll
            for (int d = 1; d < 64; d <<= 1) {
                unsigned o = __shfl_up(inc, d, 64);
                if (lane >= d) inc += o;
            }
            if (lane == 63) wtot[w] = inc;
        }
        __syncthreads();
        if (t < 256) {
            unsigned wbase = 0;
            for (int i = 0; i < w; ++i) wbase += wtot[i];
            unsigned e = wbase + inc - c;
            ex[t] = e;
            if (t == 255) tot_s = e + c;
            int half = t >> 7, nl = t & 127;
            int gnode = bucket * NPB + h * 128 + nl;
            if (gnode < n) {
                if (half == 0) { noffA[gnode] = o0 + (int)e; nendA[gnode] = o0 + (int)(e + c); }
                else           { noffB[gnode] = o0 + (int)e; nendB[gnode] = o0 + (int)(e + c); }
            }
        }
    }
    __syncthreads();
    if (t < 128) {
        unsigned ctot = cnt[t] + cnt[128 + t];
        float dv = rsqrtf((float)ctot + 1.0f);
        ldv[t] = dv;
        int gnode = bucket * NPB + h * 128 + t;
        if (gnode < n) dinv[gnode] = dv;
    }
    __syncthreads();
    // pass 2: rank-scatter into node-sorted order (ex becomes cursor)
    for (int i = t; i < used; i += 512) {
        unsigned rec = recs[e0 + i];
        unsigned node = rec >> 17;
        if ((int)(node >> 7) == h) {
            unsigned bin = (((rec & 0x1FFFFu) >= NH) ? 128u : 0u) | (node & 127u);
            unsigned pos = atomicAdd(&ex[bin], 1u);
            lsort[pos] = rec;
        }
    }
    __syncthreads();
    // coalesced write-out
    int tot = (int)tot_s;
    for (int i = t; i < tot; i += 512) srcs[o0 + i] = lsort[i];
    // fused: z = x * dinv for this half-bucket's 128 nodes (1 float4/thread)
    {
        int nl = t >> 2;
        int gnode = bucket * NPB + h * 128 + nl;
        if (gnode < n) {
            float4 v = ((const float4*)x)[(size_t)gnode * 4 + (t & 3)];
            float dv = ldv[nl];
            v.x *= dv; v.y *= dv; v.z *= dv; v.w *= dv;
            ((float4*)z)[(size_t)gnode * 4 + (t & 3)] = v;
        }
    }
}

// two-phase merge-path segmented CSR aggregation — 64 nodes/block, 256
// threads. Pass A: src < NH (gather table = lower 3.2MB, per-XCD-L2-fits);
// pass B: src >= NH. Register accumulation, LDS-atomic flush only at segment
// boundaries; 8 gathers in flight per lane.
// mode 1: out = relu(dinv*(S@W) + bias) * dinv     (layer-1 -> y)
// mode 2: out = dinv*(S@W) + bias                  (final output)
__global__ __launch_bounds__(256) void
agg_bal_kernel(const float* __restrict__ hin, const unsigned* __restrict__ srcs,
               const int* __restrict__ noffA, const int* __restrict__ nendA,
               const int* __restrict__ noffB, const int* __restrict__ nendB,
               const float* __restrict__ dinv,
               const float* __restrict__ W, const float* __restrict__ bias,
               float* __restrict__ outp, int n, int mode) {
    __shared__ float acc[64][F + 1];
    __shared__ float Ws[F * F];
    int t = threadIdx.x, b = blockIdx.x;
    int g = t >> 2, c = t & 3;          // 64 groups of 4 lanes (float4 columns)
    Ws[t] = W[t];
    for (int i = t; i < 64 * (F + 1); i += 256) ((float*)acc)[i] = 0.f;
    __syncthreads();
    int nfirst = b * 64;
    int nlast = nfirst + 63; if (nlast > n - 1) nlast = n - 1;
    int rs0 = noffA[nfirst], re0 = nendA[nlast];
    int rs1 = noffB[nfirst], re1 = nendB[nlast];
    const float4* h4 = (const float4*)hin;

#define PROC(r, v)                                                        \
    {                                                                     \
        int nd = (int)((r >> 17) & 63u);                                  \
        if (nd != cur) {                                                  \
            float* a = &acc[cur][c * 4];                                  \
            atomicAdd(a + 0, s.x); atomicAdd(a + 1, s.y);                 \
            atomicAdd(a + 2, s.z); atomicAdd(a + 3, s.w);                 \
            s.x = 0.f; s.y = 0.f; s.z = 0.f; s.w = 0.f;                   \
            cur = nd;                                                     \
        }                                                                 \
        s.x += v.x; s.y += v.y; s.z += v.z; s.w += v.w;                   \
    }

#pragma unroll 1
    for (int p = 0; p < 2; ++p) {
        int S = p ? rs1 : rs0;
        int Eend = p ? re1 : re0;
        int T = Eend - S;
        int chunk = (T + 63) >> 6;
        int gs = S + g * chunk;
        int ge = gs + chunk; if (ge > Eend) ge = Eend;
        if (gs < ge) {
            int cur = (int)((srcs[gs] >> 17) & 63u);
            float4 s = {0.f, 0.f, 0.f, 0.f};
            int e = gs;
            for (; e + 8 <= ge; e += 8) {
                unsigned r0 = srcs[e + 0], r1 = srcs[e + 1];
                unsigned r2 = srcs[e + 2], r3 = srcs[e + 3];
                unsigned r4 = srcs[e + 4], r5 = srcs[e + 5];
                unsigned r6 = srcs[e + 6], r7 = srcs[e + 7];
                float4 v0 = h4[(size_t)(r0 & 0x1FFFFu) * 4 + c];
                float4 v1 = h4[(size_t)(r1 & 0x1FFFFu) * 4 + c];
                float4 v2 = h4[(size_t)(r2 & 0x1FFFFu) * 4 + c];
                float4 v3 = h4[(size_t)(r3 & 0x1FFFFu) * 4 + c];
                float4 v4 = h4[(size_t)(r4 & 0x1FFFFu) * 4 + c];
                float4 v5 = h4[(size_t)(r5 & 0x1FFFFu) * 4 + c];
                float4 v6 = h4[(size_t)(r6 & 0x1FFFFu) * 4 + c];
                float4 v7 = h4[(size_t)(r7 & 0x1FFFFu) * 4 + c];
                PROC(r0, v0); PROC(r1, v1); PROC(r2, v2); PROC(r3, v3);
                PROC(r4, v4); PROC(r5, v5); PROC(r6, v6); PROC(r7, v7);
            }
            for (; e + 4 <= ge; e += 4) {
                unsigned r0 = srcs[e], r1 = srcs[e + 1], r2 = srcs[e + 2], r3 = srcs[e + 3];
                float4 v0 = h4[(size_t)(r0 & 0x1FFFFu) * 4 + c];
                float4 v1 = h4[(size_t)(r1 & 0x1FFFFu) * 4 + c];
                float4 v2 = h4[(size_t)(r2 & 0x1FFFFu) * 4 + c];
                float4 v3 = h4[(size_t)(r3 & 0x1FFFFu) * 4 + c];
                PROC(r0, v0); PROC(r1, v1); PROC(r2, v2); PROC(r3, v3);
            }
            for (; e < ge; ++e) {
                unsigned r0 = srcs[e];
                float4 v0 = h4[(size_t)(r0 & 0x1FFFFu) * 4 + c];
                PROC(r0, v0);
            }
            float* a = &acc[cur][c * 4];
            atomicAdd(a + 0, s.x); atomicAdd(a + 1, s.y);
            atomicAdd(a + 2, s.z); atomicAdd(a + 3, s.w);
        }
        __syncthreads();   // phase alignment across the block's waves
    }
#undef PROC
    int node = nfirst + g;
    if (node < n) {   // self contribution (unique 4 floats per thread)
        float4 self = h4[(size_t)node * 4 + c];
        float* ar = &acc[g][c * 4];
        ar[0] += self.x; ar[1] += self.y; ar[2] += self.z; ar[3] += self.w;
    }
    __syncthreads();
    if (node < n) {
        float di = dinv[node];
        float4 o = {0.f, 0.f, 0.f, 0.f};
        int j = c * 4;
#pragma unroll
        for (int k = 0; k < F; ++k) {
            float ak = acc[g][k];
            o.x += ak * Ws[k * F + j + 0];
            o.y += ak * Ws[k * F + j + 1];
            o.z += ak * Ws[k * F + j + 2];
            o.w += ak * Ws[k * F + j + 3];
        }
        float4 bi = ((const float4*)bias)[c];
        o.x = di * o.x + bi.x; o.y = di * o.y + bi.y;
        o.z = di * o.z + bi.z; o.w = di * o.w + bi.w;
        if (mode == 1) {
            o.x = fmaxf(o.x, 0.f) * di; o.y = fmaxf(o.y, 0.f) * di;
            o.z = fmaxf(o.z, 0.f) * di; o.w = fmaxf(o.w, 0.f) * di;
        }
        ((float4*)outp)[(size_t)node * 4 + c] = o;
    }
}

// ========================= fallback (R1) kernels ============================

__global__ void deg_kernel(const int* __restrict__ dst, float* __restrict__ deg, int E) {
    int e = blockIdx.x * blockDim.x + threadIdx.x;
    if (e < E) atomicAdd(&deg[dst[e]], 1.0f);
}
__global__ void dinv_kernel(float* __restrict__ deg, int n) {
    int i = blockIdx.x * blockDim.x + threadIdx.x;
    if (i < n) deg[i] = rsqrtf(deg[i] + 1.0f);
}
__global__ void linear2_kernel(const float* __restrict__ in, const float* __restrict__ acc,
                               const float* __restrict__ dinv, const float* __restrict__ W,
                               const float* __restrict__ bias, float* __restrict__ out,
                               int n, int mode) {
    __shared__ float Ws[F * F];
    __shared__ float As[16][F + 1];
    int t = threadIdx.x;
    Ws[t] = W[t];
    int nb = t >> 4, j = t & 15;
    int i = blockIdx.x * 16 + nb;
    float di = 0.f, v = 0.f;
    if (i < n) {
        di = dinv[i]; v = in[i * F + j];
        if (mode) { v = di * (acc[i * F + j] + v) + bias[j]; v = fmaxf(v, 0.f); }
    }
    As[nb][j] = v;
    __syncthreads();
    if (i < n) {
        float s = 0.f;
#pragma unroll
        for (int k = 0; k < F; ++k) s += As[nb][k] * Ws[k * F + j];
        out[i * F + j] = s * di;
    }
}
__global__ void scatter_kernel(const int* __restrict__ src, const int* __restrict__ dst,
                               const float* __restrict__ h, float* __restrict__ acc, int E) {
    int t = blockIdx.x * blockDim.x + threadIdx.x;
    int e = t >> 4, j = t & 15;
    if (e < E) atomicAdd(&acc[dst[e] * F + j], h[src[e] * F + j]);
}
__global__ void out_kernel(const float* __restrict__ acc, const float* __restrict__ h,
                           const float* __restrict__ dinv, const float* __restrict__ bias,
                           float* __restrict__ out, int n) {
    int t = blockIdx.x * blockDim.x + threadIdx.x;
    if (t < n * F) {
        int i = t >> 4, j = t & 15;
        out[t] = dinv[i] * (acc[t] + h[t]) + bias[j];
    }
}

// ========================= launch ===========================================

extern "C" void kernel_launch(void* const* d_in, const int* in_sizes, int n_in,
                              void* d_out, int out_size, void* d_ws, size_t ws_size,
                              hipStream_t stream) {
    const float* x  = (const float*)d_in[0];
    const int*   ei = (const int*)d_in[1];
    const float* W1 = (const float*)d_in[2];
    const float* b1 = (const float*)d_in[3];
    const float* W2 = (const float*)d_in[4];
    const float* b2 = (const float*)d_in[5];
    float* outp = (float*)d_out;

    const int N = in_sizes[0] / F;
    const int E = in_sizes[1] / 2;
    const int* src = ei;
    const int* dst = ei + E;

    const int nb_rt = (N + NPB - 1) >> BSHIFT;
    const size_t RC = (size_t)NB * BCAP;           // 3,603,456 entries (> 16N)
    // ws layout (4B units): dinv[N] | z[16N] | recs[RC] (y aliases) | srcs[RC] |
    //                       noffA[N] | nendA[N] | noffB[N] | nendB[N] | cursor[16*NB]
    size_t need = sizeof(unsigned) * ((size_t)N * 21 + 2 * RC + 16 * NB);

    if (nb_rt == NB && E <= CH * 65535 && ws_size >= need) {
        float* dinv = (float*)d_ws;
        float* z = dinv + N;
        unsigned* recs = (unsigned*)(z + (size_t)F * N);
        float* y = (float*)recs;                   // alias: recs dead after sort2
        unsigned* srcs = recs + RC;
        int* noffA = (int*)(srcs + RC);
        int* nendA = noffA + N;
        int* noffB = nendA + N;
        int* nendB = noffB + N;
        unsigned* cursor = (unsigned*)(nendB + N);

        init_cursor_kernel<<<1, 512, 0, stream>>>(cursor);
        reorder_kernel<<<(E + CH - 1) / CH, 512, 0, stream>>>(src, dst, cursor, recs, E);
        sort2_kernel<<<NB * 2, 512, 0, stream>>>(recs, cursor, srcs, noffA, nendA, noffB, nendB, dinv, x, z, N);
        agg_bal_kernel<<<(N + 63) / 64, 256, 0, stream>>>(z, srcs, noffA, nendA, noffB, nendB, dinv, W1, b1, y, N, 1);
        agg_bal_kernel<<<(N + 63) / 64, 256, 0, stream>>>(y, srcs, noffA, nendA, noffB, nendB, dinv, W2, b2, outp, N, 2);
    } else {
        // R1 fallback: atomic scatter path (13.2MB ws)
        float* dinv = (float*)d_ws;
        float* h = dinv + N;
        float* acc = h + (size_t)F * N;
        hipMemsetAsync(dinv, 0, (size_t)N * sizeof(float), stream);
        hipMemsetAsync(acc, 0, (size_t)F * N * sizeof(float), stream);
        deg_kernel<<<(E + 255) / 256, 256, 0, stream>>>(dst, dinv, E);
        dinv_kernel<<<(N + 255) / 256, 256, 0, stream>>>(dinv, N);
        linear2_kernel<<<(N + 15) / 16, 256, 0, stream>>>(x, nullptr, dinv, W1, nullptr, h, N, 0);
        scatter_kernel<<<((size_t)E * F + 255) / 256, 256, 0, stream>>>(src, dst, h, acc, E);
        linear2_kernel<<<(N + 15) / 16, 256, 0, stream>>>(h, acc, dinv, W2, b1, h, N, 1);
        hipMemsetAsync(acc, 0, (size_t)F * N * sizeof(float), stream);
        scatter_kernel<<<((size_t)E * F + 255) / 256, 256, 0, stream>>>(src, dst, h, acc, E);
        out_kernel<<<((size_t)N * F + 255) / 256, 256, 0, stream>>>(acc, h, dinv, b2, outp, N);
    }
}